// Round 25
// baseline (291.372 us; speedup 1.0000x reference)
//
#include <hip/hip_runtime.h>
#include <cstdint>
#include <cstddef>

#define NB 32
#define NN 1024
#define ND 256
#define KNNK 16

typedef __attribute__((ext_vector_type(8))) short bf16x8;
typedef __attribute__((ext_vector_type(4))) float f32x4;
typedef __attribute__((ext_vector_type(4))) short short4v;

// Round-to-nearest-even bf16 split (identical arithmetic to v12-v24).
__device__ __forceinline__ void bf16_split(float v, unsigned short& h,
                                           unsigned short& l) {
    uint32_t u  = __float_as_uint(v);
    uint32_t hi = (u + 0x7fffu + ((u >> 16) & 1u)) >> 16;
    float    hf = __uint_as_float(hi << 16);
    uint32_t g  = __float_as_uint(v - hf);
    uint32_t lo = (g + 0x7fffu + ((g >> 16) & 1u)) >> 16;
    h = (unsigned short)hi;
    l = (unsigned short)lo;
}

// Fragment-tiled plane layout (shorts):
//   plane[rt][c][lh][lr][i] ; rt = flat_row>>4, c = e>>5, lh = (e>>3)&3,
//   lr = flat_row&15, i = e&7 ; linear: rt*4096 + c*512 + lh*128 + lr*8 + i

// ---------------------------------------------------------------------------
// Kernel A v25: proj with 8x4 microtile (block = 128 rows x 64 e, grid 1024).
// Per d-step 4 ds_read_b128 feed 64 FMA (v17: 3 feed 32) -> LDS/barrier
// overhead per FMA halved. acc 64 regs + staging ~50 => ~115, no spill,
// 4 waves/SIMD. Hs[16][132] (528B rows, 16B-aligned; broadcast reads).
// Per-output FMA chain unchanged (dc asc, d asc) -> bit-identical planes
// (absmax must stay exactly 0.01257324).
// ---------------------------------------------------------------------------
__global__ __launch_bounds__(256) void proj_kernel(
    const float* __restrict__ x, const float* __restrict__ pos,
    const float* __restrict__ wq, const float* __restrict__ bq,
    const float* __restrict__ wk, const float* __restrict__ bk,
    unsigned short* __restrict__ Qh, unsigned short* __restrict__ Ql,
    unsigned short* __restrict__ Kh, unsigned short* __restrict__ Kl)
{
    __shared__ __align__(16) float Hs [16][132];   // [d][row], 8.4 KB
    __shared__ __align__(16) float WsQ[16][68];
    __shared__ __align__(16) float WsK[16][68];

    const int tid = threadIdx.x;
    const int tx = tid & 15;          // e microtile index (4 e)
    const int ty = tid >> 4;          // row microtile index (8 rows), 0..15
    const int bm = blockIdx.x >> 2;   // 0..255 row blocks (128 rows each)
    const int be = blockIdx.x & 3;    // 0..3 e tiles (both Q and K)
    const int rowBase = bm << 7;      // flattened b*1024 + n
    const int n0 = rowBase & 1023;
    const int e0 = be << 6;

    const int hr = tid >> 1;          // 0..127 (H staging row)
    const int hd = (tid & 1) << 3;    // 0 or 8 (H staging d base)
    const int sr = tid >> 2;          // 0..63 (W staging e)
    const int sd = (tid & 3) << 2;    // 0,4,8,12 (W staging d)

    float accQ[8][4], accK[8][4];
    #pragma unroll
    for (int i = 0; i < 8; ++i)
        #pragma unroll
        for (int j = 0; j < 4; ++j) { accQ[i][j] = 0.0f; accK[i][j] = 0.0f; }

    #pragma unroll 1
    for (int dc = 0; dc < 256; dc += 16) {
        const float4 xv0 = *(const float4*)&x  [(size_t)(rowBase + hr) * 256 + dc + hd];
        const float4 xv1 = *(const float4*)&x  [(size_t)(rowBase + hr) * 256 + dc + hd + 4];
        const float4 pv0 = *(const float4*)&pos[(size_t)(n0 + hr) * 256 + dc + hd];
        const float4 pv1 = *(const float4*)&pos[(size_t)(n0 + hr) * 256 + dc + hd + 4];
        const float4 wqv = *(const float4*)&wq [(size_t)(e0 + sr) * 256 + dc + sd];
        const float4 wkv = *(const float4*)&wk [(size_t)(e0 + sr) * 256 + dc + sd];
        __syncthreads();   // previous compute done reading LDS
        Hs [hd + 0][hr] = xv0.x + pv0.x;
        Hs [hd + 1][hr] = xv0.y + pv0.y;
        Hs [hd + 2][hr] = xv0.z + pv0.z;
        Hs [hd + 3][hr] = xv0.w + pv0.w;
        Hs [hd + 4][hr] = xv1.x + pv1.x;
        Hs [hd + 5][hr] = xv1.y + pv1.y;
        Hs [hd + 6][hr] = xv1.z + pv1.z;
        Hs [hd + 7][hr] = xv1.w + pv1.w;
        WsQ[sd + 0][sr] = wqv.x;
        WsQ[sd + 1][sr] = wqv.y;
        WsQ[sd + 2][sr] = wqv.z;
        WsQ[sd + 3][sr] = wqv.w;
        WsK[sd + 0][sr] = wkv.x;
        WsK[sd + 1][sr] = wkv.y;
        WsK[sd + 2][sr] = wkv.z;
        WsK[sd + 3][sr] = wkv.w;
        __syncthreads();
        #pragma unroll
        for (int d = 0; d < 16; ++d) {
            const float4 rv0 = *(const float4*)&Hs [d][(ty << 3) + 0];  // rows
            const float4 rv1 = *(const float4*)&Hs [d][(ty << 3) + 4];
            const float4 eq  = *(const float4*)&WsQ[d][tx << 2];        // Q e
            const float4 ek  = *(const float4*)&WsK[d][tx << 2];        // K e
            const float a8[8] = {rv0.x, rv0.y, rv0.z, rv0.w,
                                 rv1.x, rv1.y, rv1.z, rv1.w};
            const float q4[4] = {eq.x, eq.y, eq.z, eq.w};
            const float k4[4] = {ek.x, ek.y, ek.z, ek.w};
            #pragma unroll
            for (int i = 0; i < 8; ++i)
                #pragma unroll
                for (int j = 0; j < 4; ++j) {
                    accQ[i][j] = fmaf(a8[i], q4[j], accQ[i][j]);
                    accK[i][j] = fmaf(a8[i], k4[j], accK[i][j]);
                }
        }
    }

    const float4 bq4 = *(const float4*)&bq[e0 + (tx << 2)];
    const float4 bk4 = *(const float4*)&bk[e0 + (tx << 2)];
    const float bbq[4] = {bq4.x, bq4.y, bq4.z, bq4.w};
    const float bbk[4] = {bk4.x, bk4.y, bk4.z, bk4.w};
    #pragma unroll
    for (int i = 0; i < 8; ++i)
        #pragma unroll
        for (int j = 0; j < 4; ++j) {
            accQ[i][j] += bbq[j];
            accK[i][j] += bbk[j];
        }

    const int e_lo = e0 + (tx << 2);
    const int c0   = e_lo >> 5;
    const int lh0  = (e_lo >> 3) & 3;
    const int i0   = e_lo & 7;                 // 0 or 4
    #pragma unroll
    for (int i = 0; i < 8; ++i) {
        const int row = rowBase + (ty << 3) + i;
        const size_t addr = (size_t)(row >> 4) * 4096 + c0 * 512 + lh0 * 128
                          + (size_t)(row & 15) * 8 + i0;
        short4v qh4, ql4, kh4, kl4;
        #pragma unroll
        for (int j = 0; j < 4; ++j) {
            unsigned short h, l;
            bf16_split(accQ[i][j], h, l);
            qh4[j] = (short)h; ql4[j] = (short)l;
            bf16_split(accK[i][j], h, l);
            kh4[j] = (short)h; kl4[j] = (short)l;
        }
        *(short4v*)&Qh[addr] = qh4;
        *(short4v*)&Ql[addr] = ql4;
        *(short4v*)&Kh[addr] = kh4;
        *(short4v*)&Kl[addr] = kl4;
    }
}

// ---------------------------------------------------------------------------
// Kernel B1 (v24 verbatim): batched score GEMM, 128-row x 64-col tiles.
// ---------------------------------------------------------------------------
__global__ __launch_bounds__(256, 4) void score_kernel(
    const unsigned short* __restrict__ Qh, const unsigned short* __restrict__ Ql,
    const unsigned short* __restrict__ Kh, const unsigned short* __restrict__ Kl,
    float* __restrict__ out)
{
    __shared__ __align__(16) unsigned short Ah[8][512];   // 8 KB
    __shared__ __align__(16) unsigned short Al[8][512];   // 8 KB
    __shared__ __align__(16) unsigned short Bh[4][512];   // 4 KB
    __shared__ __align__(16) unsigned short Bl[4][512];   // 4 KB

    const int tid  = threadIdx.x;
    const int lane = tid & 63;
    const int w    = tid >> 6;        // 0..3
    const int lr   = lane & 15;
    const int lh   = lane >> 4;
    const int bid  = ((blockIdx.x & 7) << 9) + (blockIdx.x >> 3);  // XCD swz
    const int b    = bid >> 7;        // 0..31
    const int rg   = (bid >> 4) & 7;  // 128-row group
    const int tc   = bid & 15;        // 64-col group

    const int rtA0 = (b << 6) + (rg << 3);
    const int rtB0 = (b << 6) + (tc << 2);

    const int srt = tid >> 6;         // 0..3 (staging rt index)
    const int sln = tid & 63;
    const size_t sOff = (size_t)sln * 8;

    f32x4 acc[2][4];
    #pragma unroll
    for (int i = 0; i < 2; ++i)
        #pragma unroll
        for (int ct = 0; ct < 4; ++ct) acc[i][ct] = (f32x4){0.f, 0.f, 0.f, 0.f};

    // prologue: chunk 0 staging regs
    uint4 pAh0 = *(const uint4*)(Qh + (size_t)(rtA0 + srt) * 4096 + sOff);
    uint4 pAl0 = *(const uint4*)(Ql + (size_t)(rtA0 + srt) * 4096 + sOff);
    uint4 pAh1 = *(const uint4*)(Qh + (size_t)(rtA0 + srt + 4) * 4096 + sOff);
    uint4 pAl1 = *(const uint4*)(Ql + (size_t)(rtA0 + srt + 4) * 4096 + sOff);
    uint4 pBh  = *(const uint4*)(Kh + (size_t)(rtB0 + srt) * 4096 + sOff);
    uint4 pBl  = *(const uint4*)(Kl + (size_t)(rtB0 + srt) * 4096 + sOff);

    #pragma unroll 1
    for (int c = 0; c < 8; ++c) {
        __syncthreads();              // previous chunk's LDS reads complete
        *(uint4*)&Ah[srt][sln << 3]     = pAh0;
        *(uint4*)&Al[srt][sln << 3]     = pAl0;
        *(uint4*)&Ah[srt + 4][sln << 3] = pAh1;
        *(uint4*)&Al[srt + 4][sln << 3] = pAl1;
        *(uint4*)&Bh[srt][sln << 3]     = pBh;
        *(uint4*)&Bl[srt][sln << 3]     = pBl;
        __syncthreads();

        if (c < 7) {                  // prefetch next chunk (overlaps compute)
            const size_t cOff = (size_t)(c + 1) * 512 + sOff;
            pAh0 = *(const uint4*)(Qh + (size_t)(rtA0 + srt) * 4096 + cOff);
            pAl0 = *(const uint4*)(Ql + (size_t)(rtA0 + srt) * 4096 + cOff);
            pAh1 = *(const uint4*)(Qh + (size_t)(rtA0 + srt + 4) * 4096 + cOff);
            pAl1 = *(const uint4*)(Ql + (size_t)(rtA0 + srt + 4) * 4096 + cOff);
            pBh  = *(const uint4*)(Kh + (size_t)(rtB0 + srt) * 4096 + cOff);
            pBl  = *(const uint4*)(Kl + (size_t)(rtB0 + srt) * 4096 + cOff);
        }

        // ---- A fragments (wave's rt pair 2w, 2w+1) ----
        union { bf16x8 v; uint4 u; } ah0, al0, ah1, al1;
        ah0.u = *(const uint4*)&Ah[(w << 1) + 0][lane << 3];
        al0.u = *(const uint4*)&Al[(w << 1) + 0][lane << 3];
        ah1.u = *(const uint4*)&Ah[(w << 1) + 1][lane << 3];
        al1.u = *(const uint4*)&Al[(w << 1) + 1][lane << 3];

        #pragma unroll
        for (int ct = 0; ct < 4; ++ct) {
            union { bf16x8 v; uint4 u; } kh_, kl_;
            kh_.u = *(const uint4*)&Bh[ct][lane << 3];
            kl_.u = *(const uint4*)&Bl[ct][lane << 3];
            acc[0][ct] = __builtin_amdgcn_mfma_f32_16x16x32_bf16(ah0.v, kh_.v, acc[0][ct], 0, 0, 0);
            acc[0][ct] = __builtin_amdgcn_mfma_f32_16x16x32_bf16(ah0.v, kl_.v, acc[0][ct], 0, 0, 0);
            acc[0][ct] = __builtin_amdgcn_mfma_f32_16x16x32_bf16(al0.v, kh_.v, acc[0][ct], 0, 0, 0);
            acc[1][ct] = __builtin_amdgcn_mfma_f32_16x16x32_bf16(ah1.v, kh_.v, acc[1][ct], 0, 0, 0);
            acc[1][ct] = __builtin_amdgcn_mfma_f32_16x16x32_bf16(ah1.v, kl_.v, acc[1][ct], 0, 0, 0);
            acc[1][ct] = __builtin_amdgcn_mfma_f32_16x16x32_bf16(al1.v, kh_.v, acc[1][ct], 0, 0, 0);
        }
    }

    // D layout (hw-verified): tile row = lh*4 + reg, tile col = lr.
    #pragma unroll
    for (int i = 0; i < 2; ++i) {
        const int orow = (b << 10) + ((rg << 3) + (w << 1) + i) * 16 + (lh << 2);
        #pragma unroll
        for (int ct = 0; ct < 4; ++ct) {
            const int ocol = (tc << 6) + (ct << 4) + lr;
            float* op = out + (size_t)orow * 1024 + ocol;
            op[0]            = acc[i][ct].x;
            op[(size_t)1024] = acc[i][ct].y;
            op[(size_t)2048] = acc[i][ct].z;
            op[(size_t)3072] = acc[i][ct].w;
        }
    }
}

// ---------------------------------------------------------------------------
// Kernel B2 (v13 verbatim): softmax + top-16, in-place on out.
// ---------------------------------------------------------------------------
__global__ __launch_bounds__(256, 4) void topk_kernel(float* __restrict__ out)
{
    const int tid  = threadIdx.x;
    const int lane = tid & 63;
    const int w    = tid >> 6;
    const int rowBase = (int)(blockIdx.x << 3);

    float* __restrict__ r0p = out + (size_t)(rowBase + (w << 1) + 0) * 1024;
    float* __restrict__ r1p = out + (size_t)(rowBase + (w << 1) + 1) * 1024;

    float s0[16], s1[16];
    #pragma unroll
    for (int o = 0; o < 4; ++o) {
        const float4 a = *(const float4*)&r0p[(o << 8) + (lane << 2)];
        const float4 c = *(const float4*)&r1p[(o << 8) + (lane << 2)];
        s0[(o << 2) + 0] = a.x * 0.0625f;
        s0[(o << 2) + 1] = a.y * 0.0625f;
        s0[(o << 2) + 2] = a.z * 0.0625f;
        s0[(o << 2) + 3] = a.w * 0.0625f;
        s1[(o << 2) + 0] = c.x * 0.0625f;
        s1[(o << 2) + 1] = c.y * 0.0625f;
        s1[(o << 2) + 2] = c.z * 0.0625f;
        s1[(o << 2) + 3] = c.w * 0.0625f;
    }

    // row max (wave butterfly), both rows interleaved
    float mx0 = s0[0], mx1 = s1[0];
    #pragma unroll
    for (int i = 1; i < 16; ++i) {
        mx0 = fmaxf(mx0, s0[i]);
        mx1 = fmaxf(mx1, s1[i]);
    }
    #pragma unroll
    for (int off = 32; off > 0; off >>= 1) {
        mx0 = fmaxf(mx0, __shfl_xor(mx0, off));
        mx1 = fmaxf(mx1, __shfl_xor(mx1, off));
    }

    // softmax denominator
    float ls0 = 0.f, ls1 = 0.f;
    #pragma unroll
    for (int i = 0; i < 16; ++i) {
        ls0 += __expf(s0[i] - mx0);
        ls1 += __expf(s1[i] - mx1);
    }
    #pragma unroll
    for (int off = 32; off > 0; off >>= 1) {
        ls0 += __shfl_xor(ls0, off);
        ls1 += __shfl_xor(ls1, off);
    }
    const float rZ0 = 1.0f / ls0;
    const float rZ1 = 1.0f / ls1;

    // top-16 extraction on working copies; winners -> bitmasks
    float wv0[16], wv1[16];
    #pragma unroll
    for (int i = 0; i < 16; ++i) { wv0[i] = s0[i]; wv1[i] = s1[i]; }
    unsigned mask0 = 0u, mask1 = 0u;

    #pragma unroll 1
    for (int j = 0; j < KNNK; ++j) {
        float bv0 = wv0[0], bv1 = wv1[0];
        int   bi0 = 0,      bi1 = 0;
        #pragma unroll
        for (int i = 1; i < 16; ++i) {
            const bool c0 = wv0[i] > bv0;   // strict >, ascending slot scan
            bv0 = c0 ? wv0[i] : bv0;
            bi0 = c0 ? i      : bi0;
            const bool c1 = wv1[i] > bv1;
            bv1 = c1 ? wv1[i] : bv1;
            bi1 = c1 ? i      : bi1;
        }
        const int bm0 = ((bi0 >> 2) << 8) + (lane << 2) + (bi0 & 3);
        const int bm1 = ((bi1 >> 2) << 8) + (lane << 2) + (bi1 & 3);
        const unsigned ub0   = __float_as_uint(bv0);
        const unsigned ub1   = __float_as_uint(bv1);
        const unsigned mono0 = ub0 ^ (unsigned)(((int)ub0 >> 31) | 0x80000000);
        const unsigned mono1 = ub1 ^ (unsigned)(((int)ub1 >> 31) | 0x80000000);
        const unsigned long long key0 =
            ((unsigned long long)mono0 << 32) | (unsigned)(~bm0);
        const unsigned long long key1 =
            ((unsigned long long)mono1 << 32) | (unsigned)(~bm1);
        unsigned long long gk0 = key0, gk1 = key1;
        #pragma unroll
        for (int off = 32; off > 0; off >>= 1) {
            const unsigned long long o0 = __shfl_xor(gk0, off);
            const unsigned long long o1 = __shfl_xor(gk1, off);
            gk0 = (o0 > gk0) ? o0 : gk0;
            gk1 = (o1 > gk1) ? o1 : gk1;
        }
        if (key0 == gk0) {               // unique winner lane, row 0
            mask0 |= (1u << bi0);
            #pragma unroll
            for (int i = 0; i < 16; ++i)
                wv0[i] = (i == bi0) ? -__builtin_inff() : wv0[i];
        }
        if (key1 == gk1) {               // unique winner lane, row 1
            mask1 |= (1u << bi1);
            #pragma unroll
            for (int i = 0; i < 16; ++i)
                wv1[i] = (i == bi1) ? -__builtin_inff() : wv1[i];
        }
    }

    // full-coverage coalesced writes from pristine s0/s1
    #pragma unroll
    for (int o = 0; o < 4; ++o) {
        float4 v;
        v.x = ((mask0 >> ((o << 2) + 0)) & 1u) ? __expf(s0[(o << 2) + 0] - mx0) * rZ0 : 0.f;
        v.y = ((mask0 >> ((o << 2) + 1)) & 1u) ? __expf(s0[(o << 2) + 1] - mx0) * rZ0 : 0.f;
        v.z = ((mask0 >> ((o << 2) + 2)) & 1u) ? __expf(s0[(o << 2) + 2] - mx0) * rZ0 : 0.f;
        v.w = ((mask0 >> ((o << 2) + 3)) & 1u) ? __expf(s0[(o << 2) + 3] - mx0) * rZ0 : 0.f;
        *(float4*)&r0p[(lane << 2) + (o << 8)] = v;
    }
    #pragma unroll
    for (int o = 0; o < 4; ++o) {
        float4 v;
        v.x = ((mask1 >> ((o << 2) + 0)) & 1u) ? __expf(s1[(o << 2) + 0] - mx1) * rZ1 : 0.f;
        v.y = ((mask1 >> ((o << 2) + 1)) & 1u) ? __expf(s1[(o << 2) + 1] - mx1) * rZ1 : 0.f;
        v.z = ((mask1 >> ((o << 2) + 2)) & 1u) ? __expf(s1[(o << 2) + 2] - mx1) * rZ1 : 0.f;
        v.w = ((mask1 >> ((o << 2) + 3)) & 1u) ? __expf(s1[(o << 2) + 3] - mx1) * rZ1 : 0.f;
        *(float4*)&r1p[(lane << 2) + (o << 8)] = v;
    }
}

extern "C" void kernel_launch(void* const* d_in, const int* in_sizes, int n_in,
                              void* d_out, int out_size, void* d_ws, size_t ws_size,
                              hipStream_t stream)
{
    const float* x   = (const float*)d_in[0];
    const float* pos = (const float*)d_in[1];
    const float* wq  = (const float*)d_in[2];
    const float* bq  = (const float*)d_in[3];
    const float* wk  = (const float*)d_in[4];
    const float* bk  = (const float*)d_in[5];
    float* out = (float*)d_out;

    const size_t PLANE = (size_t)NB * NN * ND;       // 8M shorts = 16 MiB
    unsigned short* Qh = (unsigned short*)d_ws;
    unsigned short* Ql = Qh + PLANE;
    unsigned short* Kh = Ql + PLANE;
    unsigned short* Kl = Kh + PLANE;

    proj_kernel<<<dim3(1024), dim3(256), 0, stream>>>(x, pos, wq, bq, wk, bk,
                                                      Qh, Ql, Kh, Kl);
    score_kernel<<<dim3(4096), dim3(256), 0, stream>>>(Qh, Ql, Kh, Kl, out);
    topk_kernel<<<dim3(4096), dim3(256), 0, stream>>>(out);
}

// Round 26
// 279.189 us; speedup vs baseline: 1.0436x; 1.0436x over previous
//
#include <hip/hip_runtime.h>
#include <cstdint>
#include <cstddef>

#define NB 32
#define NN 1024
#define ND 256
#define KNNK 16

typedef __attribute__((ext_vector_type(8))) short bf16x8;
typedef __attribute__((ext_vector_type(4))) float f32x4;
typedef __attribute__((ext_vector_type(4))) short short4v;

// Round-to-nearest-even bf16 split (identical arithmetic to v12-v25).
__device__ __forceinline__ void bf16_split(float v, unsigned short& h,
                                           unsigned short& l) {
    uint32_t u  = __float_as_uint(v);
    uint32_t hi = (u + 0x7fffu + ((u >> 16) & 1u)) >> 16;
    float    hf = __uint_as_float(hi << 16);
    uint32_t g  = __float_as_uint(v - hf);
    uint32_t lo = (g + 0x7fffu + ((g >> 16) & 1u)) >> 16;
    h = (unsigned short)hi;
    l = (unsigned short)lo;
}

// Fragment-tiled plane layout (shorts):
//   plane[rt][c][lh][lr][i] ; rt = flat_row>>4, c = e>>5, lh = (e>>3)&3,
//   lr = flat_row&15, i = e&7 ; linear: rt*4096 + c*512 + lh*128 + lr*8 + i

// ---------------------------------------------------------------------------
// Kernel A (v17 verbatim, measured 123us — the proj optimum; v23 dbuf and
// v25 8x4-microtile both regressed via occupancy loss): fused pos-add +
// dual projection -> 4 bf16 planes in fragment-tiled layout.
// ---------------------------------------------------------------------------
__global__ __launch_bounds__(256) void proj_kernel(
    const float* __restrict__ x, const float* __restrict__ pos,
    const float* __restrict__ wq, const float* __restrict__ bq,
    const float* __restrict__ wk, const float* __restrict__ bk,
    unsigned short* __restrict__ Qh, unsigned short* __restrict__ Ql,
    unsigned short* __restrict__ Kh, unsigned short* __restrict__ Kl)
{
    __shared__ __align__(16) float Hs [16][68];
    __shared__ __align__(16) float WsQ[16][68];
    __shared__ __align__(16) float WsK[16][68];

    const int tid = threadIdx.x;
    const int tx = tid & 15;          // e microtile index
    const int ty = tid >> 4;          // row microtile index
    const int bm = blockIdx.x >> 2;   // 0..511 row tiles
    const int be = blockIdx.x & 3;    // 0..3 e tiles (both Q and K)
    const int rowBase = bm << 6;      // flattened b*1024 + n
    const int n0 = rowBase & 1023;
    const int e0 = be << 6;

    const int sr = tid >> 2;          // 0..63
    const int sd = (tid & 3) << 2;    // 0,4,8,12

    float accQ[4][4], accK[4][4];
    #pragma unroll
    for (int i = 0; i < 4; ++i)
        #pragma unroll
        for (int j = 0; j < 4; ++j) { accQ[i][j] = 0.0f; accK[i][j] = 0.0f; }

    #pragma unroll 1
    for (int dc = 0; dc < 256; dc += 16) {
        const float4 xv  = *(const float4*)&x  [(size_t)(rowBase + sr) * 256 + dc + sd];
        const float4 pv  = *(const float4*)&pos[(size_t)(n0 + sr) * 256 + dc + sd];
        const float4 wqv = *(const float4*)&wq [(size_t)(e0 + sr) * 256 + dc + sd];
        const float4 wkv = *(const float4*)&wk [(size_t)(e0 + sr) * 256 + dc + sd];
        __syncthreads();
        Hs [sd + 0][sr] = xv.x + pv.x;
        Hs [sd + 1][sr] = xv.y + pv.y;
        Hs [sd + 2][sr] = xv.z + pv.z;
        Hs [sd + 3][sr] = xv.w + pv.w;
        WsQ[sd + 0][sr] = wqv.x;
        WsQ[sd + 1][sr] = wqv.y;
        WsQ[sd + 2][sr] = wqv.z;
        WsQ[sd + 3][sr] = wqv.w;
        WsK[sd + 0][sr] = wkv.x;
        WsK[sd + 1][sr] = wkv.y;
        WsK[sd + 2][sr] = wkv.z;
        WsK[sd + 3][sr] = wkv.w;
        __syncthreads();
        #pragma unroll
        for (int d = 0; d < 16; ++d) {
            const float4 rv = *(const float4*)&Hs [d][ty << 2];
            const float4 eq = *(const float4*)&WsQ[d][tx << 2];
            const float4 ek = *(const float4*)&WsK[d][tx << 2];
            const float a4[4] = {rv.x, rv.y, rv.z, rv.w};
            const float q4[4] = {eq.x, eq.y, eq.z, eq.w};
            const float k4[4] = {ek.x, ek.y, ek.z, ek.w};
            #pragma unroll
            for (int i = 0; i < 4; ++i)
                #pragma unroll
                for (int j = 0; j < 4; ++j) {
                    accQ[i][j] = fmaf(a4[i], q4[j], accQ[i][j]);
                    accK[i][j] = fmaf(a4[i], k4[j], accK[i][j]);
                }
        }
    }

    const float4 bq4 = *(const float4*)&bq[e0 + (tx << 2)];
    const float4 bk4 = *(const float4*)&bk[e0 + (tx << 2)];
    const float bbq[4] = {bq4.x, bq4.y, bq4.z, bq4.w};
    const float bbk[4] = {bk4.x, bk4.y, bk4.z, bk4.w};
    #pragma unroll
    for (int i = 0; i < 4; ++i)
        #pragma unroll
        for (int j = 0; j < 4; ++j) {
            accQ[i][j] += bbq[j];
            accK[i][j] += bbk[j];
        }

    const int e_lo = e0 + (tx << 2);
    const int c0   = e_lo >> 5;
    const int lh0  = (e_lo >> 3) & 3;
    const int i0   = e_lo & 7;                 // 0 or 4
    #pragma unroll
    for (int i = 0; i < 4; ++i) {
        const int row = rowBase + (ty << 2) + i;
        const size_t addr = (size_t)(row >> 4) * 4096 + c0 * 512 + lh0 * 128
                          + (size_t)(row & 15) * 8 + i0;
        short4v qh4, ql4, kh4, kl4;
        #pragma unroll
        for (int j = 0; j < 4; ++j) {
            unsigned short h, l;
            bf16_split(accQ[i][j], h, l);
            qh4[j] = (short)h; ql4[j] = (short)l;
            bf16_split(accK[i][j], h, l);
            kh4[j] = (short)h; kl4[j] = (short)l;
        }
        *(short4v*)&Qh[addr] = qh4;
        *(short4v*)&Ql[addr] = ql4;
        *(short4v*)&Kh[addr] = kh4;
        *(short4v*)&Kl[addr] = kl4;
    }
}

// ---------------------------------------------------------------------------
// Kernel B1 (v24 verbatim — the score optimum): batched score GEMM,
// 128-row x 64-col tiles (grid 4096). 8 A rt + 4 B rt staged (24 KB,
// 4 blocks/CU); wave owns rt {2w,2w+1} x all 4 ct -> per chunk per wave
// 12 ds_read + 24 MFMA between barriers; acc[2][4] = 32 regs (no spill).
// ---------------------------------------------------------------------------
__global__ __launch_bounds__(256, 4) void score_kernel(
    const unsigned short* __restrict__ Qh, const unsigned short* __restrict__ Ql,
    const unsigned short* __restrict__ Kh, const unsigned short* __restrict__ Kl,
    float* __restrict__ out)
{
    __shared__ __align__(16) unsigned short Ah[8][512];   // 8 KB
    __shared__ __align__(16) unsigned short Al[8][512];   // 8 KB
    __shared__ __align__(16) unsigned short Bh[4][512];   // 4 KB
    __shared__ __align__(16) unsigned short Bl[4][512];   // 4 KB

    const int tid  = threadIdx.x;
    const int lane = tid & 63;
    const int w    = tid >> 6;        // 0..3
    const int lr   = lane & 15;
    const int lh   = lane >> 4;
    const int bid  = ((blockIdx.x & 7) << 9) + (blockIdx.x >> 3);  // XCD swz
    const int b    = bid >> 7;        // 0..31
    const int rg   = (bid >> 4) & 7;  // 128-row group
    const int tc   = bid & 15;        // 64-col group

    const int rtA0 = (b << 6) + (rg << 3);
    const int rtB0 = (b << 6) + (tc << 2);

    const int srt = tid >> 6;         // 0..3 (staging rt index)
    const int sln = tid & 63;
    const size_t sOff = (size_t)sln * 8;

    f32x4 acc[2][4];
    #pragma unroll
    for (int i = 0; i < 2; ++i)
        #pragma unroll
        for (int ct = 0; ct < 4; ++ct) acc[i][ct] = (f32x4){0.f, 0.f, 0.f, 0.f};

    // prologue: chunk 0 staging regs
    uint4 pAh0 = *(const uint4*)(Qh + (size_t)(rtA0 + srt) * 4096 + sOff);
    uint4 pAl0 = *(const uint4*)(Ql + (size_t)(rtA0 + srt) * 4096 + sOff);
    uint4 pAh1 = *(const uint4*)(Qh + (size_t)(rtA0 + srt + 4) * 4096 + sOff);
    uint4 pAl1 = *(const uint4*)(Ql + (size_t)(rtA0 + srt + 4) * 4096 + sOff);
    uint4 pBh  = *(const uint4*)(Kh + (size_t)(rtB0 + srt) * 4096 + sOff);
    uint4 pBl  = *(const uint4*)(Kl + (size_t)(rtB0 + srt) * 4096 + sOff);

    #pragma unroll 1
    for (int c = 0; c < 8; ++c) {
        __syncthreads();              // previous chunk's LDS reads complete
        *(uint4*)&Ah[srt][sln << 3]     = pAh0;
        *(uint4*)&Al[srt][sln << 3]     = pAl0;
        *(uint4*)&Ah[srt + 4][sln << 3] = pAh1;
        *(uint4*)&Al[srt + 4][sln << 3] = pAl1;
        *(uint4*)&Bh[srt][sln << 3]     = pBh;
        *(uint4*)&Bl[srt][sln << 3]     = pBl;
        __syncthreads();

        if (c < 7) {                  // prefetch next chunk (overlaps compute)
            const size_t cOff = (size_t)(c + 1) * 512 + sOff;
            pAh0 = *(const uint4*)(Qh + (size_t)(rtA0 + srt) * 4096 + cOff);
            pAl0 = *(const uint4*)(Ql + (size_t)(rtA0 + srt) * 4096 + cOff);
            pAh1 = *(const uint4*)(Qh + (size_t)(rtA0 + srt + 4) * 4096 + cOff);
            pAl1 = *(const uint4*)(Ql + (size_t)(rtA0 + srt + 4) * 4096 + cOff);
            pBh  = *(const uint4*)(Kh + (size_t)(rtB0 + srt) * 4096 + cOff);
            pBl  = *(const uint4*)(Kl + (size_t)(rtB0 + srt) * 4096 + cOff);
        }

        // ---- A fragments (wave's rt pair 2w, 2w+1) ----
        union { bf16x8 v; uint4 u; } ah0, al0, ah1, al1;
        ah0.u = *(const uint4*)&Ah[(w << 1) + 0][lane << 3];
        al0.u = *(const uint4*)&Al[(w << 1) + 0][lane << 3];
        ah1.u = *(const uint4*)&Ah[(w << 1) + 1][lane << 3];
        al1.u = *(const uint4*)&Al[(w << 1) + 1][lane << 3];

        #pragma unroll
        for (int ct = 0; ct < 4; ++ct) {
            union { bf16x8 v; uint4 u; } kh_, kl_;
            kh_.u = *(const uint4*)&Bh[ct][lane << 3];
            kl_.u = *(const uint4*)&Bl[ct][lane << 3];
            acc[0][ct] = __builtin_amdgcn_mfma_f32_16x16x32_bf16(ah0.v, kh_.v, acc[0][ct], 0, 0, 0);
            acc[0][ct] = __builtin_amdgcn_mfma_f32_16x16x32_bf16(ah0.v, kl_.v, acc[0][ct], 0, 0, 0);
            acc[0][ct] = __builtin_amdgcn_mfma_f32_16x16x32_bf16(al0.v, kh_.v, acc[0][ct], 0, 0, 0);
            acc[1][ct] = __builtin_amdgcn_mfma_f32_16x16x32_bf16(ah1.v, kh_.v, acc[1][ct], 0, 0, 0);
            acc[1][ct] = __builtin_amdgcn_mfma_f32_16x16x32_bf16(ah1.v, kl_.v, acc[1][ct], 0, 0, 0);
            acc[1][ct] = __builtin_amdgcn_mfma_f32_16x16x32_bf16(al1.v, kh_.v, acc[1][ct], 0, 0, 0);
        }
    }

    // D layout (hw-verified): tile row = lh*4 + reg, tile col = lr.
    #pragma unroll
    for (int i = 0; i < 2; ++i) {
        const int orow = (b << 10) + ((rg << 3) + (w << 1) + i) * 16 + (lh << 2);
        #pragma unroll
        for (int ct = 0; ct < 4; ++ct) {
            const int ocol = (tc << 6) + (ct << 4) + lr;
            float* op = out + (size_t)orow * 1024 + ocol;
            op[0]            = acc[i][ct].x;
            op[(size_t)1024] = acc[i][ct].y;
            op[(size_t)2048] = acc[i][ct].z;
            op[(size_t)3072] = acc[i][ct].w;
        }
    }
}

// ---------------------------------------------------------------------------
// Kernel B2 (v13 verbatim): softmax + top-16, in-place on out.
// ---------------------------------------------------------------------------
__global__ __launch_bounds__(256, 4) void topk_kernel(float* __restrict__ out)
{
    const int tid  = threadIdx.x;
    const int lane = tid & 63;
    const int w    = tid >> 6;
    const int rowBase = (int)(blockIdx.x << 3);

    float* __restrict__ r0p = out + (size_t)(rowBase + (w << 1) + 0) * 1024;
    float* __restrict__ r1p = out + (size_t)(rowBase + (w << 1) + 1) * 1024;

    float s0[16], s1[16];
    #pragma unroll
    for (int o = 0; o < 4; ++o) {
        const float4 a = *(const float4*)&r0p[(o << 8) + (lane << 2)];
        const float4 c = *(const float4*)&r1p[(o << 8) + (lane << 2)];
        s0[(o << 2) + 0] = a.x * 0.0625f;
        s0[(o << 2) + 1] = a.y * 0.0625f;
        s0[(o << 2) + 2] = a.z * 0.0625f;
        s0[(o << 2) + 3] = a.w * 0.0625f;
        s1[(o << 2) + 0] = c.x * 0.0625f;
        s1[(o << 2) + 1] = c.y * 0.0625f;
        s1[(o << 2) + 2] = c.z * 0.0625f;
        s1[(o << 2) + 3] = c.w * 0.0625f;
    }

    // row max (wave butterfly), both rows interleaved
    float mx0 = s0[0], mx1 = s1[0];
    #pragma unroll
    for (int i = 1; i < 16; ++i) {
        mx0 = fmaxf(mx0, s0[i]);
        mx1 = fmaxf(mx1, s1[i]);
    }
    #pragma unroll
    for (int off = 32; off > 0; off >>= 1) {
        mx0 = fmaxf(mx0, __shfl_xor(mx0, off));
        mx1 = fmaxf(mx1, __shfl_xor(mx1, off));
    }

    // softmax denominator
    float ls0 = 0.f, ls1 = 0.f;
    #pragma unroll
    for (int i = 0; i < 16; ++i) {
        ls0 += __expf(s0[i] - mx0);
        ls1 += __expf(s1[i] - mx1);
    }
    #pragma unroll
    for (int off = 32; off > 0; off >>= 1) {
        ls0 += __shfl_xor(ls0, off);
        ls1 += __shfl_xor(ls1, off);
    }
    const float rZ0 = 1.0f / ls0;
    const float rZ1 = 1.0f / ls1;

    // top-16 extraction on working copies; winners -> bitmasks
    float wv0[16], wv1[16];
    #pragma unroll
    for (int i = 0; i < 16; ++i) { wv0[i] = s0[i]; wv1[i] = s1[i]; }
    unsigned mask0 = 0u, mask1 = 0u;

    #pragma unroll 1
    for (int j = 0; j < KNNK; ++j) {
        float bv0 = wv0[0], bv1 = wv1[0];
        int   bi0 = 0,      bi1 = 0;
        #pragma unroll
        for (int i = 1; i < 16; ++i) {
            const bool c0 = wv0[i] > bv0;   // strict >, ascending slot scan
            bv0 = c0 ? wv0[i] : bv0;
            bi0 = c0 ? i      : bi0;
            const bool c1 = wv1[i] > bv1;
            bv1 = c1 ? wv1[i] : bv1;
            bi1 = c1 ? i      : bi1;
        }
        const int bm0 = ((bi0 >> 2) << 8) + (lane << 2) + (bi0 & 3);
        const int bm1 = ((bi1 >> 2) << 8) + (lane << 2) + (bi1 & 3);
        const unsigned ub0   = __float_as_uint(bv0);
        const unsigned ub1   = __float_as_uint(bv1);
        const unsigned mono0 = ub0 ^ (unsigned)(((int)ub0 >> 31) | 0x80000000);
        const unsigned mono1 = ub1 ^ (unsigned)(((int)ub1 >> 31) | 0x80000000);
        const unsigned long long key0 =
            ((unsigned long long)mono0 << 32) | (unsigned)(~bm0);
        const unsigned long long key1 =
            ((unsigned long long)mono1 << 32) | (unsigned)(~bm1);
        unsigned long long gk0 = key0, gk1 = key1;
        #pragma unroll
        for (int off = 32; off > 0; off >>= 1) {
            const unsigned long long o0 = __shfl_xor(gk0, off);
            const unsigned long long o1 = __shfl_xor(gk1, off);
            gk0 = (o0 > gk0) ? o0 : gk0;
            gk1 = (o1 > gk1) ? o1 : gk1;
        }
        if (key0 == gk0) {               // unique winner lane, row 0
            mask0 |= (1u << bi0);
            #pragma unroll
            for (int i = 0; i < 16; ++i)
                wv0[i] = (i == bi0) ? -__builtin_inff() : wv0[i];
        }
        if (key1 == gk1) {               // unique winner lane, row 1
            mask1 |= (1u << bi1);
            #pragma unroll
            for (int i = 0; i < 16; ++i)
                wv1[i] = (i == bi1) ? -__builtin_inff() : wv1[i];
        }
    }

    // full-coverage coalesced writes from pristine s0/s1
    #pragma unroll
    for (int o = 0; o < 4; ++o) {
        float4 v;
        v.x = ((mask0 >> ((o << 2) + 0)) & 1u) ? __expf(s0[(o << 2) + 0] - mx0) * rZ0 : 0.f;
        v.y = ((mask0 >> ((o << 2) + 1)) & 1u) ? __expf(s0[(o << 2) + 1] - mx0) * rZ0 : 0.f;
        v.z = ((mask0 >> ((o << 2) + 2)) & 1u) ? __expf(s0[(o << 2) + 2] - mx0) * rZ0 : 0.f;
        v.w = ((mask0 >> ((o << 2) + 3)) & 1u) ? __expf(s0[(o << 2) + 3] - mx0) * rZ0 : 0.f;
        *(float4*)&r0p[(lane << 2) + (o << 8)] = v;
    }
    #pragma unroll
    for (int o = 0; o < 4; ++o) {
        float4 v;
        v.x = ((mask1 >> ((o << 2) + 0)) & 1u) ? __expf(s1[(o << 2) + 0] - mx1) * rZ1 : 0.f;
        v.y = ((mask1 >> ((o << 2) + 1)) & 1u) ? __expf(s1[(o << 2) + 1] - mx1) * rZ1 : 0.f;
        v.z = ((mask1 >> ((o << 2) + 2)) & 1u) ? __expf(s1[(o << 2) + 2] - mx1) * rZ1 : 0.f;
        v.w = ((mask1 >> ((o << 2) + 3)) & 1u) ? __expf(s1[(o << 2) + 3] - mx1) * rZ1 : 0.f;
        *(float4*)&r1p[(lane << 2) + (o << 8)] = v;
    }
}

extern "C" void kernel_launch(void* const* d_in, const int* in_sizes, int n_in,
                              void* d_out, int out_size, void* d_ws, size_t ws_size,
                              hipStream_t stream)
{
    const float* x   = (const float*)d_in[0];
    const float* pos = (const float*)d_in[1];
    const float* wq  = (const float*)d_in[2];
    const float* bq  = (const float*)d_in[3];
    const float* wk  = (const float*)d_in[4];
    const float* bk  = (const float*)d_in[5];
    float* out = (float*)d_out;

    const size_t PLANE = (size_t)NB * NN * ND;       // 8M shorts = 16 MiB
    unsigned short* Qh = (unsigned short*)d_ws;
    unsigned short* Ql = Qh + PLANE;
    unsigned short* Kh = Ql + PLANE;
    unsigned short* Kl = Kh + PLANE;

    proj_kernel<<<dim3(2048), dim3(256), 0, stream>>>(x, pos, wq, bq, wk, bk,
                                                      Qh, Ql, Kh, Kl);
    score_kernel<<<dim3(4096), dim3(256), 0, stream>>>(Qh, Ql, Kh, Kl, out);
    topk_kernel<<<dim3(4096), dim3(256), 0, stream>>>(out);
}